// Round 1
// baseline (1126.398 us; speedup 1.0000x reference)
//
#include <hip/hip_runtime.h>

// ---------------- problem constants (from reference) ----------------
constexpr int cN0 = 200000, cN1 = 50000, cN2 = 10000;
constexpr int cE0 = 800000, cE1 = 160000;
constexpr int GD  = 144;   // 32+16+16+16+64 sparse concat dim
constexpr int HID = 256, OUTD = 128;

// ---------------- embedding slot mapping ----------------
struct Slot { const float* base; int xs; int dim; };

__device__ __forceinline__ Slot make_slot(int j,
    const float* t0, const float* t1, const float* t2,
    const float* t3, const float* t4) {
  Slot s;
  if (j < 32)      { s.base = t0 + j;      s.xs = 0; s.dim = 32; }
  else if (j < 48) { s.base = t1 + (j-32); s.xs = 1; s.dim = 16; }
  else if (j < 64) { s.base = t2 + (j-48); s.xs = 2; s.dim = 16; }
  else if (j < 80) { s.base = t3 + (j-64); s.xs = 3; s.dim = 16; }
  else             { s.base = t4 + (j-80); s.xs = 4; s.dim = 64; }
  return s;
}

// ---------------- CSR build ----------------
__global__ __launch_bounds__(256)
void count_kernel(const int* __restrict__ d, int* __restrict__ cnt, int E) {
  int i = blockIdx.x * blockDim.x + threadIdx.x;
  if (i < E) atomicAdd(&cnt[d[i]], 1);
}

__global__ __launch_bounds__(1024)
void scan_kernel(const int* __restrict__ cnt, int* __restrict__ rp, int n) {
  __shared__ int sums[1024];
  __shared__ int s_carry;
  if (threadIdx.x == 0) s_carry = 0;
  __syncthreads();
  const int V = 4;
  const int chunk = 1024 * V;
  for (int base = 0; base < n; base += chunk) {
    int idx0 = base + (int)threadIdx.x * V;
    int v[V];
    int s = 0;
    #pragma unroll
    for (int i = 0; i < V; ++i) {
      int id = idx0 + i;
      v[i] = (id < n) ? cnt[id] : 0;
      s += v[i];
    }
    sums[threadIdx.x] = s;
    __syncthreads();
    for (int off = 1; off < 1024; off <<= 1) {
      int t = (threadIdx.x >= off) ? sums[threadIdx.x - off] : 0;
      __syncthreads();
      sums[threadIdx.x] += t;
      __syncthreads();
    }
    int incl = sums[threadIdx.x];
    int excl = incl - s;
    int run = s_carry + excl;
    #pragma unroll
    for (int i = 0; i < V; ++i) {
      int id = idx0 + i;
      if (id < n) rp[id] = run;
      run += v[i];
    }
    __syncthreads();
    if (threadIdx.x == 1023) s_carry += sums[1023];
    __syncthreads();
  }
  if (threadIdx.x == 0) rp[n] = s_carry;
}

__global__ __launch_bounds__(256)
void scatter_kernel(const int* __restrict__ s, const int* __restrict__ d,
                    const int* __restrict__ rp, int* __restrict__ fill,
                    int* __restrict__ out, int E) {
  int i = blockIdx.x * blockDim.x + threadIdx.x;
  if (i < E) {
    int dd = d[i];
    int p = atomicAdd(&fill[dd], 1);
    out[rp[dd] + p] = s[i];
  }
}

// ---------------- layer-0 fused embedding aggregation ----------------
// one wave per dst node: u[d] = g_self[d] + mean_{src in-nbrs} g[src]   (144-dim)
__global__ __launch_bounds__(256)
void agg0_kernel(const int* __restrict__ x,
                 const float* __restrict__ t0, const float* __restrict__ t1,
                 const float* __restrict__ t2, const float* __restrict__ t3,
                 const float* __restrict__ t4,
                 const int* __restrict__ rp, const int* __restrict__ srcs,
                 float* __restrict__ u) {
  int wid  = blockIdx.x * 4 + (threadIdx.x >> 6);
  int lane = threadIdx.x & 63;
  if (wid >= cN1) return;
  Slot s0 = make_slot(lane,        t0, t1, t2, t3, t4);
  Slot s1 = make_slot(lane + 64,   t0, t1, t2, t3, t4);
  bool has2 = (lane < 16);
  Slot s2 = make_slot(has2 ? lane + 128 : 143, t0, t1, t2, t3, t4);

  int beg = rp[wid], end = rp[wid + 1];
  float a0 = 0.f, a1 = 0.f, a2 = 0.f;
  for (int e = beg; e < end; ++e) {
    const int* xr = x + (size_t)srcs[e] * 5;
    a0 += s0.base[xr[s0.xs] * s0.dim];
    a1 += s1.base[xr[s1.xs] * s1.dim];
    if (has2) a2 += s2.base[xr[s2.xs] * s2.dim];
  }
  float invc = (end > beg) ? 1.f / (float)(end - beg) : 0.f;
  const int* xd = x + (size_t)wid * 5;
  float* ur = u + (size_t)wid * GD;
  ur[lane]      = s0.base[xd[s0.xs] * s0.dim] + a0 * invc;
  ur[64 + lane] = s1.base[xd[s1.xs] * s1.dim] + a1 * invc;
  if (has2)
    ur[128 + lane] = s2.base[xd[s2.xs] * s2.dim] + a2 * invc;
}

// ---------------- layer-1 aggregation (256-dim) ----------------
__global__ __launch_bounds__(256)
void agg1_kernel(const float* __restrict__ h1, const int* __restrict__ rp,
                 const int* __restrict__ srcs, float* __restrict__ v) {
  int wid  = blockIdx.x * 4 + (threadIdx.x >> 6);
  int lane = threadIdx.x & 63;
  if (wid >= cN2) return;
  int beg = rp[wid], end = rp[wid + 1];
  float4 acc = make_float4(0.f, 0.f, 0.f, 0.f);
  for (int e = beg; e < end; ++e) {
    const float4 hv = reinterpret_cast<const float4*>(h1 + (size_t)srcs[e] * HID)[lane];
    acc.x += hv.x; acc.y += hv.y; acc.z += hv.z; acc.w += hv.w;
  }
  float invc = (end > beg) ? 1.f / (float)(end - beg) : 0.f;
  const float4 dv = reinterpret_cast<const float4*>(h1 + (size_t)wid * HID)[lane];
  float4 o;
  o.x = dv.x + acc.x * invc;
  o.y = dv.y + acc.y * invc;
  o.z = dv.z + acc.z * invc;
  o.w = dv.w + acc.w * invc;
  reinterpret_cast<float4*>(v + (size_t)wid * HID)[lane] = o;
}

// ---------------- generic small GEMM: C = act(c2*(A@B) + bias*bm + c0*X + c1*Y) ----------------
// A: [M,K], B: [K,NCOL] row-major. NCOL == blockDim.x.
template <int NCOL, int RTILE>
__global__ __launch_bounds__(NCOL)
void gemm_k(const float* __restrict__ A, const float* __restrict__ B,
            const float* __restrict__ bias, const int* __restrict__ rp,
            const float* __restrict__ Xa, const float* __restrict__ Ya,
            const float* __restrict__ a1p, const float* __restrict__ a2p,
            const float* __restrict__ b2p,
            float* __restrict__ C, int M, int K, int relu) {
  __shared__ float As[RTILE * 256];
  int row0 = blockIdx.x * RTILE;
  for (int r = 0; r < RTILE; ++r) {
    int row = row0 + r;
    const float* Ar = A + (size_t)row * K;
    for (int c = threadIdx.x; c < K; c += NCOL)
      As[r * K + c] = (row < M) ? Ar[c] : 0.f;
  }
  __syncthreads();
  int col = threadIdx.x;
  float acc[RTILE];
  #pragma unroll
  for (int r = 0; r < RTILE; ++r) acc[r] = 0.f;
  for (int k = 0; k < K; k += 4) {
    float w0 = B[(k + 0) * NCOL + col];
    float w1 = B[(k + 1) * NCOL + col];
    float w2 = B[(k + 2) * NCOL + col];
    float w3 = B[(k + 3) * NCOL + col];
    #pragma unroll
    for (int r = 0; r < RTILE; ++r) {
      const float4 a = *reinterpret_cast<const float4*>(&As[r * K + k]);
      acc[r] = fmaf(a.x, w0, fmaf(a.y, w1, fmaf(a.z, w2, fmaf(a.w, w3, acc[r]))));
    }
  }
  float c0 = 0.f, c1 = 0.f, c2 = 1.f;
  if (a2p) {
    float A1 = a1p[0], A2 = a2p[0], B2 = b2p[0];
    c0 = 1.f - A2 - B2;
    c1 = A2 + B2 * (1.f - A1);
    c2 = A1 * B2;
  }
  for (int r = 0; r < RTILE; ++r) {
    int row = row0 + r;
    if (row >= M) break;
    float val = acc[r] * c2;
    if (bias) {
      float bm = 1.f;
      if (rp) bm = (rp[row + 1] > rp[row]) ? 2.f : 1.f;
      val += bias[col] * bm;
    }
    if (Xa) val += c0 * Xa[(size_t)row * NCOL + col];
    if (Ya) val += c1 * Ya[(size_t)row * NCOL + col];
    if (relu) val = fmaxf(val, 0.f);
    C[(size_t)row * NCOL + col] = val;
  }
}

// ---------------- launch ----------------
extern "C" void kernel_launch(void* const* d_in, const int* in_sizes, int n_in,
                              void* d_out, int out_size, void* d_ws, size_t ws_size,
                              hipStream_t stream) {
  const int* x = (const int*)d_in[0];

  struct Branch {
    const int *e0s, *e0d, *e1s, *e1d;
    const float *t0, *t1, *t2, *t3, *t4, *Win, *bin, *Wout, *bout;
  };
  auto mk = [&](int b) {
    Branch B;
    B.e0s = (const int*)d_in[b + 0];
    B.e0d = (const int*)d_in[b + 1];
    B.e1s = (const int*)d_in[b + 2];
    B.e1d = (const int*)d_in[b + 3];
    B.t0  = (const float*)d_in[b + 4];
    B.t1  = (const float*)d_in[b + 5];
    B.t2  = (const float*)d_in[b + 6];
    B.t3  = (const float*)d_in[b + 7];
    B.t4  = (const float*)d_in[b + 8];
    B.Win = (const float*)d_in[b + 9];
    B.bin = (const float*)d_in[b + 10];
    B.Wout= (const float*)d_in[b + 11];
    B.bout= (const float*)d_in[b + 12];
    return B;
  };
  Branch SB = mk(1), CB = mk(14);
  const float* Ws2c = (const float*)d_in[27];
  const float* Wc2s = (const float*)d_in[28];
  const float* a1p  = (const float*)d_in[29];
  const float* a2p  = (const float*)d_in[30];
  const float* b2p  = (const float*)d_in[31];

  // workspace layout (bytes, 256-aligned)
  char* ws = (char*)d_ws;
  float* u    = (float*)(ws + 0);          //  50000*144*4 = 28,800,000
  float* h1   = (float*)(ws + 28800000);   //  50000*256*4 = 51,200,000
  float* v    = (float*)(ws + 80000000);   //  10000*256*4 = 10,240,000
  float* simb = (float*)(ws + 90240000);   //  10000*128*4 =  5,120,000
  float* corb = (float*)(ws + 95360000);
  float* tmp1 = (float*)(ws + 100480000);
  float* tmp2 = (float*)(ws + 105600000);
  int*   rp     = (int*)(ws + 110720000);  // 50001 ints
  int*   cnt    = (int*)(ws + 110920192);  // 50000 ints
  int*   sorted = (int*)(ws + 111120384);  // 800000 ints  (end ~114.3 MB)

  auto run_branch = [&](const Branch& B, float* outbuf) {
    // --- layer 0 CSR ---
    hipMemsetAsync(cnt, 0, cN1 * sizeof(int), stream);
    count_kernel<<<(cE0 + 255) / 256, 256, 0, stream>>>(B.e0d, cnt, cE0);
    scan_kernel<<<1, 1024, 0, stream>>>(cnt, rp, cN1);
    hipMemsetAsync(cnt, 0, cN1 * sizeof(int), stream);
    scatter_kernel<<<(cE0 + 255) / 256, 256, 0, stream>>>(B.e0s, B.e0d, rp, cnt, sorted, cE0);
    // --- fused embedding + mean-agg -> u [N1,144] ---
    agg0_kernel<<<(cN1 + 3) / 4, 256, 0, stream>>>(x, B.t0, B.t1, B.t2, B.t3, B.t4,
                                                   rp, sorted, u);
    // --- h1 = relu(u @ W_in + b_in * (1 + [deg>0])) ---
    gemm_k<256, 16><<<cN1 / 16, 256, 0, stream>>>(u, B.Win, B.bin, rp,
                                                  nullptr, nullptr, nullptr, nullptr, nullptr,
                                                  h1, cN1, GD, 1);
    // --- layer 1 CSR ---
    hipMemsetAsync(cnt, 0, cN1 * sizeof(int), stream);
    count_kernel<<<(cE1 + 255) / 256, 256, 0, stream>>>(B.e1d, cnt, cE1);
    scan_kernel<<<1, 1024, 0, stream>>>(cnt, rp, cN2);
    hipMemsetAsync(cnt, 0, cN1 * sizeof(int), stream);
    scatter_kernel<<<(cE1 + 255) / 256, 256, 0, stream>>>(B.e1s, B.e1d, rp, cnt, sorted, cE1);
    // --- v = h1[:N2] + mean-agg(h1) ---
    agg1_kernel<<<(cN2 + 3) / 4, 256, 0, stream>>>(h1, rp, sorted, v);
    // --- out = v @ W_out + b_out ---
    gemm_k<128, 16><<<cN2 / 16, 128, 0, stream>>>(v, B.Wout, B.bout, nullptr,
                                                  nullptr, nullptr, nullptr, nullptr, nullptr,
                                                  outbuf, cN2, HID, 0);
  };

  run_branch(SB, simb);
  run_branch(CB, corb);

  // --- semantic integration ---
  // tmp1 = sim @ W_sim2cor ; tmp2 = cor @ W_cor2sim
  gemm_k<128, 16><<<cN2 / 16, 128, 0, stream>>>(simb, Ws2c, nullptr, nullptr,
                                                nullptr, nullptr, nullptr, nullptr, nullptr,
                                                tmp1, cN2, OUTD, 0);
  gemm_k<128, 16><<<cN2 / 16, 128, 0, stream>>>(corb, Wc2s, nullptr, nullptr,
                                                nullptr, nullptr, nullptr, nullptr, nullptr,
                                                tmp2, cN2, OUTD, 0);
  float* out = (float*)d_out;
  // z2sim = c0*sim + c1*tmp2 + c2*(tmp1 @ W_cor2sim)
  gemm_k<128, 16><<<cN2 / 16, 128, 0, stream>>>(tmp1, Wc2s, nullptr, nullptr,
                                                simb, tmp2, a1p, a2p, b2p,
                                                out, cN2, OUTD, 0);
  // z2cor = c0*cor + c1*tmp1 + c2*(tmp2 @ W_sim2cor)
  gemm_k<128, 16><<<cN2 / 16, 128, 0, stream>>>(tmp2, Ws2c, nullptr, nullptr,
                                                corb, tmp1, a1p, a2p, b2p,
                                                out + (size_t)cN2 * OUTD, cN2, OUTD, 0);
}

// Round 2
// 849.898 us; speedup vs baseline: 1.3253x; 1.3253x over previous
//
#include <hip/hip_runtime.h>

// ---------------- problem constants (from reference) ----------------
constexpr int cN0 = 200000, cN1 = 50000, cN2 = 10000;
constexpr int cE0 = 800000, cE1 = 160000;
constexpr int GD  = 144;   // 32+16+16+16+64 sparse concat dim
constexpr int HID = 256, OUTD = 128;

// ---------------- embedding slot mapping ----------------
struct Slot { const float* base; int xs; int dim; };

__device__ __forceinline__ Slot make_slot(int j,
    const float* t0, const float* t1, const float* t2,
    const float* t3, const float* t4) {
  Slot s;
  if (j < 32)      { s.base = t0 + j;      s.xs = 0; s.dim = 32; }
  else if (j < 48) { s.base = t1 + (j-32); s.xs = 1; s.dim = 16; }
  else if (j < 64) { s.base = t2 + (j-48); s.xs = 2; s.dim = 16; }
  else if (j < 80) { s.base = t3 + (j-64); s.xs = 3; s.dim = 16; }
  else             { s.base = t4 + (j-80); s.xs = 4; s.dim = 64; }
  return s;
}

// ---------------- CSR build ----------------
__global__ __launch_bounds__(256)
void count_kernel(const int* __restrict__ d, int* __restrict__ cnt, int E) {
  int i = blockIdx.x * blockDim.x + threadIdx.x;
  if (i < E) atomicAdd(&cnt[d[i]], 1);
}

__global__ __launch_bounds__(1024)
void scan_kernel(const int* __restrict__ cnt, int* __restrict__ rp, int n) {
  __shared__ int sums[1024];
  __shared__ int s_carry;
  if (threadIdx.x == 0) s_carry = 0;
  __syncthreads();
  const int V = 4;
  const int chunk = 1024 * V;
  for (int base = 0; base < n; base += chunk) {
    int idx0 = base + (int)threadIdx.x * V;
    int v[V];
    int s = 0;
    #pragma unroll
    for (int i = 0; i < V; ++i) {
      int id = idx0 + i;
      v[i] = (id < n) ? cnt[id] : 0;
      s += v[i];
    }
    sums[threadIdx.x] = s;
    __syncthreads();
    for (int off = 1; off < 1024; off <<= 1) {
      int t = (threadIdx.x >= off) ? sums[threadIdx.x - off] : 0;
      __syncthreads();
      sums[threadIdx.x] += t;
      __syncthreads();
    }
    int incl = sums[threadIdx.x];
    int excl = incl - s;
    int run = s_carry + excl;
    #pragma unroll
    for (int i = 0; i < V; ++i) {
      int id = idx0 + i;
      if (id < n) rp[id] = run;
      run += v[i];
    }
    __syncthreads();
    if (threadIdx.x == 1023) s_carry += sums[1023];
    __syncthreads();
  }
  if (threadIdx.x == 0) rp[n] = s_carry;
}

__global__ __launch_bounds__(256)
void scatter_kernel(const int* __restrict__ s, const int* __restrict__ d,
                    const int* __restrict__ rp, int* __restrict__ fill,
                    int* __restrict__ out, int E) {
  int i = blockIdx.x * blockDim.x + threadIdx.x;
  if (i < E) {
    int dd = d[i];
    int p = atomicAdd(&fill[dd], 1);
    out[rp[dd] + p] = s[i];
  }
}

// ---------------- layer-0 fused embedding aggregation ----------------
// one wave per dst node; cooperative 64-edge staging of (src, x-row) then
// 4-deep pipelined table gathers. Tables are L2-hot (~576 KB touched).
__global__ __launch_bounds__(256)
void agg0_kernel(const int* __restrict__ x,
                 const float* __restrict__ t0, const float* __restrict__ t1,
                 const float* __restrict__ t2, const float* __restrict__ t3,
                 const float* __restrict__ t4,
                 const int* __restrict__ rp, const int* __restrict__ srcs,
                 float* __restrict__ u) {
  __shared__ int lx[4][64 * 5];
  int w    = threadIdx.x >> 6;
  int wid  = blockIdx.x * 4 + w;
  int lane = threadIdx.x & 63;
  if (wid >= cN1) return;
  Slot s0 = make_slot(lane,      t0, t1, t2, t3, t4);
  Slot s1 = make_slot(lane + 64, t0, t1, t2, t3, t4);
  bool has2 = (lane < 16);
  Slot s2 = make_slot(has2 ? lane + 128 : 143, t0, t1, t2, t3, t4);
  int* lxw = lx[w];

  int beg = rp[wid], end = rp[wid + 1];
  float a0 = 0.f, a1 = 0.f, a2v = 0.f;
  for (int base = beg; base < end; base += 64) {
    int nn = min(64, end - base);
    if (lane < nn) {
      int sidx = srcs[base + lane];
      const int* xp = x + (size_t)sidx * 5;
      int v0 = xp[0], v1 = xp[1], v2 = xp[2], v3 = xp[3], v4 = xp[4];
      int* q = lxw + lane * 5;
      q[0] = v0; q[1] = v1; q[2] = v2; q[3] = v3; q[4] = v4;
    }
    int e = 0;
    for (; e + 4 <= nn; e += 4) {
      int r0[4], r1[4], r2[4];
      #pragma unroll
      for (int q = 0; q < 4; ++q) {
        const int* xe = lxw + (e + q) * 5;
        r0[q] = xe[s0.xs];
        r1[q] = xe[s1.xs];
        r2[q] = has2 ? xe[s2.xs] : 0;
      }
      #pragma unroll
      for (int q = 0; q < 4; ++q) {
        a0 += s0.base[(size_t)r0[q] * s0.dim];
        a1 += s1.base[(size_t)r1[q] * s1.dim];
        if (has2) a2v += s2.base[(size_t)r2[q] * s2.dim];
      }
    }
    for (; e < nn; ++e) {
      const int* xe = lxw + e * 5;
      a0 += s0.base[(size_t)xe[s0.xs] * s0.dim];
      a1 += s1.base[(size_t)xe[s1.xs] * s1.dim];
      if (has2) a2v += s2.base[(size_t)xe[s2.xs] * s2.dim];
    }
  }
  float invc = (end > beg) ? 1.f / (float)(end - beg) : 0.f;
  const int* xd = x + (size_t)wid * 5;
  float* ur = u + (size_t)wid * GD;
  ur[lane]      = s0.base[(size_t)xd[s0.xs] * s0.dim] + a0 * invc;
  ur[64 + lane] = s1.base[(size_t)xd[s1.xs] * s1.dim] + a1 * invc;
  if (has2)
    ur[128 + lane] = s2.base[(size_t)xd[s2.xs] * s2.dim] + a2v * invc;
}

// ---------------- layer-1 aggregation (256-dim) ----------------
__global__ __launch_bounds__(256)
void agg1_kernel(const float* __restrict__ h1, const int* __restrict__ rp,
                 const int* __restrict__ srcs, float* __restrict__ v) {
  int wid  = blockIdx.x * 4 + (threadIdx.x >> 6);
  int lane = threadIdx.x & 63;
  if (wid >= cN2) return;
  int beg = rp[wid], end = rp[wid + 1];
  float4 acc = make_float4(0.f, 0.f, 0.f, 0.f);
  for (int base = beg; base < end; base += 64) {
    int nn = min(64, end - base);
    int se = (lane < nn) ? srcs[base + lane] : 0;
    int e = 0;
    for (; e + 4 <= nn; e += 4) {
      float4 hv[4];
      #pragma unroll
      for (int q = 0; q < 4; ++q) {
        int s = __shfl(se, e + q);
        hv[q] = reinterpret_cast<const float4*>(h1 + (size_t)s * HID)[lane];
      }
      #pragma unroll
      for (int q = 0; q < 4; ++q) {
        acc.x += hv[q].x; acc.y += hv[q].y; acc.z += hv[q].z; acc.w += hv[q].w;
      }
    }
    for (; e < nn; ++e) {
      int s = __shfl(se, e);
      const float4 hv = reinterpret_cast<const float4*>(h1 + (size_t)s * HID)[lane];
      acc.x += hv.x; acc.y += hv.y; acc.z += hv.z; acc.w += hv.w;
    }
  }
  float invc = (end > beg) ? 1.f / (float)(end - beg) : 0.f;
  const float4 dv = reinterpret_cast<const float4*>(h1 + (size_t)wid * HID)[lane];
  float4 o;
  o.x = dv.x + acc.x * invc;
  o.y = dv.y + acc.y * invc;
  o.z = dv.z + acc.z * invc;
  o.w = dv.w + acc.w * invc;
  reinterpret_cast<float4*>(v + (size_t)wid * HID)[lane] = o;
}

// ---------------- register-blocked GEMM ----------------
// 64-thread (1-wave) blocks; each thread computes RTILE rows x CPT cols.
// C = act(A@B + bias*bm + c0*X); A:[M,K], B:[K,NCOL] row-major.
template <int K, int NCOL, int CPT, int RTILE>
__global__ __launch_bounds__(64)
void gemm_k(const float* __restrict__ A, const float* __restrict__ B,
            const float* __restrict__ bias, const int* __restrict__ rp,
            const float* __restrict__ Xa, int ldx,
            const float* __restrict__ a2p, const float* __restrict__ b2p,
            float* __restrict__ C, int ldc, int M, int relu) {
  __shared__ float As[RTILE][K];
  int row0 = blockIdx.x * RTILE;
  constexpr int KV = K / 4;
  for (int i = threadIdx.x; i < RTILE * KV; i += 64) {
    int r = i / KV, c = i - r * KV;
    int row = row0 + r;
    float4 val = (row < M) ? reinterpret_cast<const float4*>(A + (size_t)row * K)[c]
                           : make_float4(0.f, 0.f, 0.f, 0.f);
    reinterpret_cast<float4*>(&As[r][0])[c] = val;
  }
  __syncthreads();
  int col0 = (int)threadIdx.x * CPT;
  float acc[RTILE][CPT];
  #pragma unroll
  for (int r = 0; r < RTILE; ++r)
    #pragma unroll
    for (int c = 0; c < CPT; ++c) acc[r][c] = 0.f;

  #pragma unroll 2
  for (int k = 0; k < K; k += 4) {
    float w[4][CPT];
    #pragma unroll
    for (int kk = 0; kk < 4; ++kk)
      #pragma unroll
      for (int c = 0; c < CPT; ++c)
        w[kk][c] = B[(size_t)(k + kk) * NCOL + col0 + c];
    #pragma unroll
    for (int r = 0; r < RTILE; ++r) {
      const float4 a = *reinterpret_cast<const float4*>(&As[r][k]);
      #pragma unroll
      for (int c = 0; c < CPT; ++c)
        acc[r][c] = fmaf(a.x, w[0][c], fmaf(a.y, w[1][c],
                    fmaf(a.z, w[2][c], fmaf(a.w, w[3][c], acc[r][c]))));
    }
  }
  float c0 = 0.f;
  if (a2p) c0 = 1.f - a2p[0] - b2p[0];
  for (int r = 0; r < RTILE; ++r) {
    int row = row0 + r;
    if (row >= M) break;
    float bm = 1.f;
    if (bias && rp) bm = (rp[row + 1] > rp[row]) ? 2.f : 1.f;
    #pragma unroll
    for (int c = 0; c < CPT; ++c) {
      float val = acc[r][c];
      int col = col0 + c;
      if (bias) val += bias[col] * bm;
      if (Xa)   val += c0 * Xa[(size_t)row * ldx + col];
      if (relu) val = fmaxf(val, 0.f);
      C[(size_t)row * ldc + col] = val;
    }
  }
}

// ---------------- stacked integration weights ----------------
// Wss = [ c2*(Ws2c@Wc2s) ; c1*Wc2s ]   (applied to hb=[sim|cor] -> z2sim - c0*sim)
// Wcs = [ c1*Ws2c ; c2*(Wc2s@Ws2c) ]   (applied to hb=[sim|cor] -> z2cor - c0*cor)
__global__ __launch_bounds__(128)
void build_wstack(const float* __restrict__ Ws2c, const float* __restrict__ Wc2s,
                  const float* __restrict__ a1p, const float* __restrict__ a2p,
                  const float* __restrict__ b2p,
                  float* __restrict__ Wss, float* __restrict__ Wcs) {
  int c = threadIdx.x;   // 0..127
  int r = blockIdx.x;    // 0..255
  float A1 = a1p[0], A2 = a2p[0], B2 = b2p[0];
  float c1 = A2 + B2 * (1.f - A1);
  float c2 = A1 * B2;
  if (r < 128) {
    float s = 0.f;
    for (int k = 0; k < 128; ++k) s += Ws2c[r * 128 + k] * Wc2s[k * 128 + c];
    Wss[r * 128 + c] = c2 * s;
    Wcs[r * 128 + c] = c1 * Ws2c[r * 128 + c];
  } else {
    int rr = r - 128;
    Wss[r * 128 + c] = c1 * Wc2s[rr * 128 + c];
    float s = 0.f;
    for (int k = 0; k < 128; ++k) s += Wc2s[rr * 128 + k] * Ws2c[k * 128 + c];
    Wcs[r * 128 + c] = c2 * s;
  }
}

// ---------------- launch ----------------
extern "C" void kernel_launch(void* const* d_in, const int* in_sizes, int n_in,
                              void* d_out, int out_size, void* d_ws, size_t ws_size,
                              hipStream_t stream) {
  const int* x = (const int*)d_in[0];

  struct Branch {
    const int *e0s, *e0d, *e1s, *e1d;
    const float *t0, *t1, *t2, *t3, *t4, *Win, *bin, *Wout, *bout;
  };
  auto mk = [&](int b) {
    Branch B;
    B.e0s = (const int*)d_in[b + 0];
    B.e0d = (const int*)d_in[b + 1];
    B.e1s = (const int*)d_in[b + 2];
    B.e1d = (const int*)d_in[b + 3];
    B.t0  = (const float*)d_in[b + 4];
    B.t1  = (const float*)d_in[b + 5];
    B.t2  = (const float*)d_in[b + 6];
    B.t3  = (const float*)d_in[b + 7];
    B.t4  = (const float*)d_in[b + 8];
    B.Win = (const float*)d_in[b + 9];
    B.bin = (const float*)d_in[b + 10];
    B.Wout= (const float*)d_in[b + 11];
    B.bout= (const float*)d_in[b + 12];
    return B;
  };
  Branch SB = mk(1), CB = mk(14);
  const float* Ws2c = (const float*)d_in[27];
  const float* Wc2s = (const float*)d_in[28];
  const float* a1p  = (const float*)d_in[29];
  const float* a2p  = (const float*)d_in[30];
  const float* b2p  = (const float*)d_in[31];

  // workspace layout (bytes)
  char* ws = (char*)d_ws;
  float* u    = (float*)(ws + 0);            // 50000*144*4 = 28,800,000
  float* h1   = (float*)(ws + 28800000);     // 50000*256*4 = 51,200,000
  float* v    = (float*)(ws + 80000000);     // 10000*256*4 = 10,240,000
  float* hb   = (float*)(ws + 90240000);     // 10000*256*4 = 10,240,000 ([sim|cor])
  float* Wss  = (float*)(ws + 100480000);    // 256*128*4 = 131,072
  float* Wcs  = (float*)(ws + 100611072);    // 131,072
  int*   rp     = (int*)(ws + 100742144);    // 50001 ints
  int*   cnt    = (int*)(ws + 100942336);    // 50000 ints
  int*   sorted = (int*)(ws + 101142336);    // 800000 ints (end ~104.3 MB)

  // independent of branches — launch first
  build_wstack<<<256, 128, 0, stream>>>(Ws2c, Wc2s, a1p, a2p, b2p, Wss, Wcs);

  auto run_branch = [&](const Branch& B, int hb_off) {
    // --- layer 0 CSR ---
    hipMemsetAsync(cnt, 0, cN1 * sizeof(int), stream);
    count_kernel<<<(cE0 + 255) / 256, 256, 0, stream>>>(B.e0d, cnt, cE0);
    scan_kernel<<<1, 1024, 0, stream>>>(cnt, rp, cN1);
    hipMemsetAsync(cnt, 0, cN1 * sizeof(int), stream);
    scatter_kernel<<<(cE0 + 255) / 256, 256, 0, stream>>>(B.e0s, B.e0d, rp, cnt, sorted, cE0);
    // --- fused embedding + mean-agg -> u [N1,144] ---
    agg0_kernel<<<(cN1 + 3) / 4, 256, 0, stream>>>(x, B.t0, B.t1, B.t2, B.t3, B.t4,
                                                   rp, sorted, u);
    // --- h1 = relu(u @ W_in + b_in * (1 + [deg>0])) ---
    gemm_k<144, 256, 4, 16><<<cN1 / 16, 64, 0, stream>>>(
        u, B.Win, B.bin, rp, nullptr, 0, nullptr, nullptr, h1, 256, cN1, 1);
    // --- layer 1 CSR ---
    hipMemsetAsync(cnt, 0, cN2 * sizeof(int), stream);
    count_kernel<<<(cE1 + 255) / 256, 256, 0, stream>>>(B.e1d, cnt, cE1);
    scan_kernel<<<1, 1024, 0, stream>>>(cnt, rp, cN2);
    hipMemsetAsync(cnt, 0, cN2 * sizeof(int), stream);
    scatter_kernel<<<(cE1 + 255) / 256, 256, 0, stream>>>(B.e1s, B.e1d, rp, cnt, sorted, cE1);
    // --- v = h1[:N2] + mean-agg(h1) ---
    agg1_kernel<<<(cN2 + 3) / 4, 256, 0, stream>>>(h1, rp, sorted, v);
    // --- hb[:, off:off+128] = v @ W_out + b_out ---
    gemm_k<256, 128, 2, 16><<<cN2 / 16, 64, 0, stream>>>(
        v, B.Wout, B.bout, nullptr, nullptr, 0, nullptr, nullptr,
        hb + hb_off, 256, cN2, 0);
  };

  run_branch(SB, 0);
  run_branch(CB, 128);

  float* out = (float*)d_out;
  // z2sim = hb @ Wss + c0*sim ; z2cor = hb @ Wcs + c0*cor
  gemm_k<256, 128, 2, 16><<<cN2 / 16, 64, 0, stream>>>(
      hb, Wss, nullptr, nullptr, hb + 0, 256, a2p, b2p, out, 128, cN2, 0);
  gemm_k<256, 128, 2, 16><<<cN2 / 16, 64, 0, stream>>>(
      hb, Wcs, nullptr, nullptr, hb + 128, 256, a2p, b2p,
      out + (size_t)cN2 * OUTD, 128, cN2, 0);
}

// Round 3
// 728.723 us; speedup vs baseline: 1.5457x; 1.1663x over previous
//
#include <hip/hip_runtime.h>

// ---------------- problem constants (from reference) ----------------
constexpr int cN0 = 200000, cN1 = 50000, cN2 = 10000;
constexpr int cE0 = 800000, cE1 = 160000;
constexpr int GD  = 144;   // 32+16+16+16+64 sparse concat dim
constexpr int KP  = 160;   // GD padded to multiple of 32 for MFMA K-steps
constexpr int HID = 256, OUTD = 128;

typedef __attribute__((ext_vector_type(8))) short bf16x8;
typedef __attribute__((ext_vector_type(4))) float f32x4;

__device__ __forceinline__ ushort f2bf(float f) {
  union { float f; unsigned u; } v; v.f = f;
  unsigned r = (v.u + 0x7FFFu + ((v.u >> 16) & 1u)) >> 16;
  return (ushort)r;
}

// ---------------- CSR build ----------------
__global__ __launch_bounds__(256)
void count_kernel(const int* __restrict__ d, int* __restrict__ cnt, int E) {
  int i = blockIdx.x * blockDim.x + threadIdx.x;
  if (i < E) atomicAdd(&cnt[d[i]], 1);
}

__global__ __launch_bounds__(1024)
void scan_kernel(const int* __restrict__ cnt, int* __restrict__ rp, int n) {
  __shared__ int wsum[16];
  __shared__ int carry_s;
  int lane = threadIdx.x & 63, wv = threadIdx.x >> 6;
  if (threadIdx.x == 0) carry_s = 0;
  __syncthreads();
  const int V = 4, chunk = 4096;
  for (int base = 0; base < n; base += chunk) {
    int idx0 = base + (int)threadIdx.x * V;
    int v[V], s = 0;
    #pragma unroll
    for (int i = 0; i < V; ++i) {
      int id = idx0 + i;
      v[i] = (id < n) ? cnt[id] : 0;
      s += v[i];
    }
    int tot = s;
    #pragma unroll
    for (int off = 1; off < 64; off <<= 1) {
      int t = __shfl_up(s, off);
      if (lane >= off) s += t;
    }
    if (lane == 63) wsum[wv] = s;
    __syncthreads();
    if (wv == 0) {
      int xch = (lane < 16) ? wsum[lane] : 0;
      #pragma unroll
      for (int off = 1; off < 16; off <<= 1) {
        int t = __shfl_up(xch, off);
        if (lane >= off) xch += t;
      }
      if (lane < 16) wsum[lane] = xch;
    }
    __syncthreads();
    int run = carry_s + (wv > 0 ? wsum[wv - 1] : 0) + (s - tot);
    #pragma unroll
    for (int i = 0; i < V; ++i) {
      int id = idx0 + i;
      if (id < n) rp[id] = run;
      run += v[i];
    }
    __syncthreads();
    if (threadIdx.x == 0) carry_s += wsum[15];
    __syncthreads();
  }
  if (threadIdx.x == 0) rp[n] = carry_s;
}

__global__ __launch_bounds__(256)
void scatter_kernel(const int* __restrict__ s, const int* __restrict__ d,
                    const int* __restrict__ rp, int* __restrict__ fill,
                    int* __restrict__ out, int E) {
  int i = blockIdx.x * blockDim.x + threadIdx.x;
  if (i < E) {
    int dd = d[i];
    int p = atomicAdd(&fill[dd], 1);
    out[rp[dd] + p] = s[i];
  }
}

// ---------------- layer-0 fused embedding aggregation (float4 gathers) ----
// lane<36 owns 4 consecutive concat-dims, all within one table.
// u output is bf16 [*, KP] with zero pad in cols 144..159.
__global__ __launch_bounds__(256)
void agg0_kernel(const int* __restrict__ x,
                 const float* __restrict__ t0, const float* __restrict__ t1,
                 const float* __restrict__ t2, const float* __restrict__ t3,
                 const float* __restrict__ t4,
                 const int* __restrict__ rp, const int* __restrict__ srcs,
                 ushort* __restrict__ u) {
  __shared__ int lx[4][64 * 5];
  int w    = threadIdx.x >> 6;
  int wid  = blockIdx.x * 4 + w;
  int lane = threadIdx.x & 63;
  if (wid >= cN1) return;
  const float* gbase; int gxs, gstride;
  if (lane < 8)       { gbase = t0 + lane * 4;        gxs = 0; gstride = 32; }
  else if (lane < 12) { gbase = t1 + (lane - 8) * 4;  gxs = 1; gstride = 16; }
  else if (lane < 16) { gbase = t2 + (lane - 12) * 4; gxs = 2; gstride = 16; }
  else if (lane < 20) { gbase = t3 + (lane - 16) * 4; gxs = 3; gstride = 16; }
  else if (lane < 36) { gbase = t4 + (lane - 20) * 4; gxs = 4; gstride = 64; }
  else                { gbase = t0;                   gxs = 0; gstride = 0;  }
  int* lxw = lx[w];

  int beg = rp[wid], end = rp[wid + 1];
  float4 acc = make_float4(0.f, 0.f, 0.f, 0.f);
  for (int base = beg; base < end; base += 64) {
    int nn = min(64, end - base);
    if (lane < nn) {
      const int* xp = x + (size_t)srcs[base + lane] * 5;
      int v0 = xp[0], v1 = xp[1], v2 = xp[2], v3 = xp[3], v4 = xp[4];
      int* q = lxw + lane * 5;
      q[0] = v0; q[1] = v1; q[2] = v2; q[3] = v3; q[4] = v4;
    }
    int e = 0;
    for (; e + 8 <= nn; e += 8) {
      int rr[8];
      #pragma unroll
      for (int q = 0; q < 8; ++q) rr[q] = lxw[(e + q) * 5 + gxs];
      float4 g[8];
      #pragma unroll
      for (int q = 0; q < 8; ++q)
        g[q] = *reinterpret_cast<const float4*>(gbase + (size_t)rr[q] * gstride);
      #pragma unroll
      for (int q = 0; q < 8; ++q) {
        acc.x += g[q].x; acc.y += g[q].y; acc.z += g[q].z; acc.w += g[q].w;
      }
    }
    for (; e < nn; ++e) {
      int r = lxw[e * 5 + gxs];
      const float4 g = *reinterpret_cast<const float4*>(gbase + (size_t)r * gstride);
      acc.x += g.x; acc.y += g.y; acc.z += g.z; acc.w += g.w;
    }
  }
  float invc = (end > beg) ? 1.f / (float)(end - beg) : 0.f;
  ushort* ur = u + (size_t)wid * KP;
  if (lane < 36) {
    const int* xd = x + (size_t)wid * 5;
    const float4 sv = *reinterpret_cast<const float4*>(gbase + (size_t)xd[gxs] * gstride);
    float4 r;
    r.x = sv.x + acc.x * invc;
    r.y = sv.y + acc.y * invc;
    r.z = sv.z + acc.z * invc;
    r.w = sv.w + acc.w * invc;
    ushort4 o;
    o.x = f2bf(r.x); o.y = f2bf(r.y); o.z = f2bf(r.z); o.w = f2bf(r.w);
    *reinterpret_cast<ushort4*>(ur + lane * 4) = o;
  } else if (lane < 40) {
    *reinterpret_cast<ushort4*>(ur + lane * 4) = make_ushort4(0, 0, 0, 0);
  }
}

// ---------------- W_in transpose + bf16 + pad: Wt[256][KP] ----------------
__global__ __launch_bounds__(KP)
void build_wt(const float* __restrict__ W, ushort* __restrict__ Wt) {
  int n = blockIdx.x, k = threadIdx.x;
  Wt[n * KP + k] = (k < GD) ? f2bf(W[(size_t)k * HID + n]) : (ushort)0;
}

// ---------------- MFMA GEMM: h1 = relu(u @ Wt^T + bias*bm) ----------------
// u bf16 [*,KP], Wt bf16 [256][KP], C fp32 [M][256].
// block 256 = 4 waves; wave computes 16 rows x 256 cols.
__global__ __launch_bounds__(256)
void gemm_mfma(const ushort* __restrict__ U, const ushort* __restrict__ Wt,
               const float* __restrict__ bias, const int* __restrict__ rp,
               float* __restrict__ C, int M) {
  int w = threadIdx.x >> 6, lane = threadIdx.x & 63;
  int l15 = lane & 15, lhi = lane >> 4;
  int rowW = blockIdx.x * 64 + w * 16;
  f32x4 acc[16];
  #pragma unroll
  for (int t = 0; t < 16; ++t) acc[t] = (f32x4){0.f, 0.f, 0.f, 0.f};
  int arow = rowW + l15; if (arow >= M) arow = M - 1;
  const ushort* up = U + (size_t)arow * KP + lhi * 8;
  const ushort* wp = Wt + (size_t)l15 * KP + lhi * 8;
  #pragma unroll
  for (int ks = 0; ks < 5; ++ks) {
    bf16x8 a = *reinterpret_cast<const bf16x8*>(up + ks * 32);
    #pragma unroll
    for (int t = 0; t < 16; ++t) {
      bf16x8 b = *reinterpret_cast<const bf16x8*>(wp + (size_t)t * 16 * KP + ks * 32);
      acc[t] = __builtin_amdgcn_mfma_f32_16x16x32_bf16(a, b, acc[t], 0, 0, 0);
    }
  }
  int r0 = rowW + lhi * 4;
  #pragma unroll
  for (int r = 0; r < 4; ++r) {
    int row = r0 + r;
    if (row >= M) continue;
    float bm = (rp[row + 1] > rp[row]) ? 2.f : 1.f;
    #pragma unroll
    for (int t = 0; t < 16; ++t) {
      float val = acc[t][r] + bias[t * 16 + l15] * bm;
      C[(size_t)row * HID + t * 16 + l15] = fmaxf(val, 0.f);
    }
  }
}

// ---------------- layer-1 aggregation (256-dim) ----------------
__global__ __launch_bounds__(256)
void agg1_kernel(const float* __restrict__ h1, const int* __restrict__ rp,
                 const int* __restrict__ srcs, float* __restrict__ v) {
  int wid  = blockIdx.x * 4 + (threadIdx.x >> 6);
  int lane = threadIdx.x & 63;
  if (wid >= cN2) return;
  int beg = rp[wid], end = rp[wid + 1];
  float4 acc = make_float4(0.f, 0.f, 0.f, 0.f);
  for (int base = beg; base < end; base += 64) {
    int nn = min(64, end - base);
    int se = (lane < nn) ? srcs[base + lane] : 0;
    int e = 0;
    for (; e + 4 <= nn; e += 4) {
      float4 hv[4];
      #pragma unroll
      for (int q = 0; q < 4; ++q) {
        int s = __shfl(se, e + q);
        hv[q] = reinterpret_cast<const float4*>(h1 + (size_t)s * HID)[lane];
      }
      #pragma unroll
      for (int q = 0; q < 4; ++q) {
        acc.x += hv[q].x; acc.y += hv[q].y; acc.z += hv[q].z; acc.w += hv[q].w;
      }
    }
    for (; e < nn; ++e) {
      int s = __shfl(se, e);
      const float4 hv = reinterpret_cast<const float4*>(h1 + (size_t)s * HID)[lane];
      acc.x += hv.x; acc.y += hv.y; acc.z += hv.z; acc.w += hv.w;
    }
  }
  float invc = (end > beg) ? 1.f / (float)(end - beg) : 0.f;
  const float4 dv = reinterpret_cast<const float4*>(h1 + (size_t)wid * HID)[lane];
  float4 o;
  o.x = dv.x + acc.x * invc;
  o.y = dv.y + acc.y * invc;
  o.z = dv.z + acc.z * invc;
  o.w = dv.w + acc.w * invc;
  reinterpret_cast<float4*>(v + (size_t)wid * HID)[lane] = o;
}

// ---------------- register-blocked fp32 GEMM (small layers) ----------------
template <int K, int NCOL, int CPT, int RTILE>
__global__ __launch_bounds__(64)
void gemm_k(const float* __restrict__ A, const float* __restrict__ B,
            const float* __restrict__ bias,
            const float* __restrict__ Xa, int ldx,
            const float* __restrict__ a2p, const float* __restrict__ b2p,
            float* __restrict__ C, int ldc, int M, int relu) {
  __shared__ float As[RTILE][K];
  int row0 = blockIdx.x * RTILE;
  constexpr int KV = K / 4;
  for (int i = threadIdx.x; i < RTILE * KV; i += 64) {
    int r = i / KV, c = i - r * KV;
    int row = row0 + r;
    float4 val = (row < M) ? reinterpret_cast<const float4*>(A + (size_t)row * K)[c]
                           : make_float4(0.f, 0.f, 0.f, 0.f);
    reinterpret_cast<float4*>(&As[r][0])[c] = val;
  }
  __syncthreads();
  int col0 = (int)threadIdx.x * CPT;
  float acc[RTILE][CPT];
  #pragma unroll
  for (int r = 0; r < RTILE; ++r)
    #pragma unroll
    for (int c = 0; c < CPT; ++c) acc[r][c] = 0.f;

  #pragma unroll 2
  for (int k = 0; k < K; k += 4) {
    float w[4][CPT];
    #pragma unroll
    for (int kk = 0; kk < 4; ++kk)
      #pragma unroll
      for (int c = 0; c < CPT; ++c)
        w[kk][c] = B[(size_t)(k + kk) * NCOL + col0 + c];
    #pragma unroll
    for (int r = 0; r < RTILE; ++r) {
      const float4 a = *reinterpret_cast<const float4*>(&As[r][k]);
      #pragma unroll
      for (int c = 0; c < CPT; ++c)
        acc[r][c] = fmaf(a.x, w[0][c], fmaf(a.y, w[1][c],
                    fmaf(a.z, w[2][c], fmaf(a.w, w[3][c], acc[r][c]))));
    }
  }
  float c0 = 0.f;
  if (a2p) c0 = 1.f - a2p[0] - b2p[0];
  for (int r = 0; r < RTILE; ++r) {
    int row = row0 + r;
    if (row >= M) break;
    #pragma unroll
    for (int c = 0; c < CPT; ++c) {
      float val = acc[r][c];
      int col = col0 + c;
      if (bias) val += bias[col];
      if (Xa)   val += c0 * Xa[(size_t)row * ldx + col];
      if (relu) val = fmaxf(val, 0.f);
      C[(size_t)row * ldc + col] = val;
    }
  }
}

// ---------------- stacked integration weights ----------------
__global__ __launch_bounds__(128)
void build_wstack(const float* __restrict__ Ws2c, const float* __restrict__ Wc2s,
                  const float* __restrict__ a1p, const float* __restrict__ a2p,
                  const float* __restrict__ b2p,
                  float* __restrict__ Wss, float* __restrict__ Wcs) {
  int c = threadIdx.x;
  int r = blockIdx.x;
  float A1 = a1p[0], A2 = a2p[0], B2 = b2p[0];
  float c1 = A2 + B2 * (1.f - A1);
  float c2 = A1 * B2;
  if (r < 128) {
    float s = 0.f;
    for (int k = 0; k < 128; ++k) s += Ws2c[r * 128 + k] * Wc2s[k * 128 + c];
    Wss[r * 128 + c] = c2 * s;
    Wcs[r * 128 + c] = c1 * Ws2c[r * 128 + c];
  } else {
    int rr = r - 128;
    Wss[r * 128 + c] = c1 * Wc2s[rr * 128 + c];
    float s = 0.f;
    for (int k = 0; k < 128; ++k) s += Wc2s[rr * 128 + k] * Ws2c[k * 128 + c];
    Wcs[r * 128 + c] = c2 * s;
  }
}

// ---------------- launch ----------------
extern "C" void kernel_launch(void* const* d_in, const int* in_sizes, int n_in,
                              void* d_out, int out_size, void* d_ws, size_t ws_size,
                              hipStream_t stream) {
  const int* x = (const int*)d_in[0];

  struct Branch {
    const int *e0s, *e0d, *e1s, *e1d;
    const float *t0, *t1, *t2, *t3, *t4, *Win, *bin, *Wout, *bout;
  };
  auto mk = [&](int b) {
    Branch B;
    B.e0s = (const int*)d_in[b + 0];
    B.e0d = (const int*)d_in[b + 1];
    B.e1s = (const int*)d_in[b + 2];
    B.e1d = (const int*)d_in[b + 3];
    B.t0  = (const float*)d_in[b + 4];
    B.t1  = (const float*)d_in[b + 5];
    B.t2  = (const float*)d_in[b + 6];
    B.t3  = (const float*)d_in[b + 7];
    B.t4  = (const float*)d_in[b + 8];
    B.Win = (const float*)d_in[b + 9];
    B.bin = (const float*)d_in[b + 10];
    B.Wout= (const float*)d_in[b + 11];
    B.bout= (const float*)d_in[b + 12];
    return B;
  };
  Branch SB = mk(1), CB = mk(14);
  const float* Ws2c = (const float*)d_in[27];
  const float* Wc2s = (const float*)d_in[28];
  const float* a1p  = (const float*)d_in[29];
  const float* a2p  = (const float*)d_in[30];
  const float* b2p  = (const float*)d_in[31];

  // workspace layout (bytes, 16B-aligned offsets)
  char* ws = (char*)d_ws;
  ushort* u   = (ushort*)(ws + 0);           // 50048*160*2 = 16,015,360
  float* h1   = (float*)(ws + 16100000);     // 50000*256*4 = 51,200,000
  float* v    = (float*)(ws + 67300000);     // 10000*256*4 = 10,240,000
  float* hb   = (float*)(ws + 77540000);     // 10,240,000 ([sim|cor])
  float* Wss  = (float*)(ws + 87780000);     // 131,072
  float* Wcs  = (float*)(ws + 87911072);     // 131,072
  ushort* Wt  = (ushort*)(ws + 88042144);    // 256*160*2 = 81,920
  int*   rp     = (int*)(ws + 88124064);     // 50001 ints
  int*   cnt    = (int*)(ws + 88324080);     // 50000 ints
  int*   sorted = (int*)(ws + 88524080);     // 800000 ints (end ~91.7 MB)

  build_wstack<<<256, 128, 0, stream>>>(Ws2c, Wc2s, a1p, a2p, b2p, Wss, Wcs);

  auto run_branch = [&](const Branch& B, int hb_off) {
    build_wt<<<HID, KP, 0, stream>>>(B.Win, Wt);
    // --- layer 0 CSR ---
    hipMemsetAsync(cnt, 0, cN1 * sizeof(int), stream);
    count_kernel<<<(cE0 + 255) / 256, 256, 0, stream>>>(B.e0d, cnt, cE0);
    scan_kernel<<<1, 1024, 0, stream>>>(cnt, rp, cN1);
    hipMemsetAsync(cnt, 0, cN1 * sizeof(int), stream);
    scatter_kernel<<<(cE0 + 255) / 256, 256, 0, stream>>>(B.e0s, B.e0d, rp, cnt, sorted, cE0);
    // --- fused embedding + mean-agg -> u bf16 [N1,KP] ---
    agg0_kernel<<<(cN1 + 3) / 4, 256, 0, stream>>>(x, B.t0, B.t1, B.t2, B.t3, B.t4,
                                                   rp, sorted, u);
    // --- h1 = relu(u @ Wt^T + b_in * (1 + [deg>0])) via MFMA ---
    gemm_mfma<<<(cN1 + 63) / 64, 256, 0, stream>>>(u, Wt, B.bin, rp, h1, cN1);
    // --- layer 1 CSR ---
    hipMemsetAsync(cnt, 0, cN2 * sizeof(int), stream);
    count_kernel<<<(cE1 + 255) / 256, 256, 0, stream>>>(B.e1d, cnt, cE1);
    scan_kernel<<<1, 1024, 0, stream>>>(cnt, rp, cN2);
    hipMemsetAsync(cnt, 0, cN2 * sizeof(int), stream);
    scatter_kernel<<<(cE1 + 255) / 256, 256, 0, stream>>>(B.e1s, B.e1d, rp, cnt, sorted, cE1);
    // --- v = h1[:N2] + mean-agg(h1) ---
    agg1_kernel<<<(cN2 + 3) / 4, 256, 0, stream>>>(h1, rp, sorted, v);
    // --- hb[:, off:off+128] = v @ W_out + b_out ---
    gemm_k<256, 128, 2, 16><<<cN2 / 16, 64, 0, stream>>>(
        v, B.Wout, B.bout, nullptr, 0, nullptr, nullptr,
        hb + hb_off, 256, cN2, 0);
  };

  run_branch(SB, 0);
  run_branch(CB, 128);

  float* out = (float*)d_out;
  gemm_k<256, 128, 2, 16><<<cN2 / 16, 64, 0, stream>>>(
      hb, Wss, nullptr, hb + 0, 256, a2p, b2p, out, 128, cN2, 0);
  gemm_k<256, 128, 2, 16><<<cN2 / 16, 64, 0, stream>>>(
      hb, Wcs, nullptr, hb + 128, 256, a2p, b2p,
      out + (size_t)cN2 * OUTD, 128, cN2, 0);
}

// Round 4
// 478.943 us; speedup vs baseline: 2.3518x; 1.5215x over previous
//
#include <hip/hip_runtime.h>

// ---------------- problem constants ----------------
constexpr int cN0 = 200000, cN1 = 50000, cN2 = 10000;
constexpr int cE0 = 800000, cE1 = 160000;
constexpr int GD  = 144;       // 32+16+16+16+64
constexpr int KP  = 160;       // padded K for MFMA
constexpr int HID = 256, OUTD = 128;
constexpr int KT  = 512;       // tail K = 2*HID

constexpr int NB_E0 = (cE0 + 255) / 256;   // 3125
constexpr int NB_E1 = (cE1 + 255) / 256;   // 625
constexpr int NC0   = (cN1 + 4095) / 4096; // 13
constexpr int NC1   = (cN2 + 4095) / 4096; // 3
constexpr int AGG0_NB = (cN1 + 3) / 4;     // 12500
constexpr int AGG1_NB = (cN2 + 3) / 4;     // 2500
constexpr int NB1   = (cN1 + 63) / 64;     // 782
constexpr int TAIL_NB = cN2 / 16;          // 625
constexpr size_t UPLANE = (size_t)50048 * KP;

typedef __attribute__((ext_vector_type(8))) short bf16x8;
typedef __attribute__((ext_vector_type(4))) float f32x4;

__device__ __forceinline__ ushort f2bf(float f) {
  union { float f; unsigned u; } v; v.f = f;
  unsigned r = (v.u + 0x7FFFu + ((v.u >> 16) & 1u)) >> 16;
  return (ushort)r;
}
__device__ __forceinline__ float bf2f(ushort u) {
  union { unsigned u; float f; } v; v.u = ((unsigned)u) << 16;
  return v.f;
}

// ---------------- CSR build (batched over 2 branches) ----------------
__global__ __launch_bounds__(256)
void count2_kernel(const int* __restrict__ d0, const int* __restrict__ d1,
                   int* __restrict__ cnt, int n, int E, int nb) {
  int br = blockIdx.x / nb;
  int i = (blockIdx.x - br * nb) * 256 + threadIdx.x;
  const int* d = br ? d1 : d0;
  if (i < E) atomicAdd(&cnt[br * n + d[i]], 1);
}

// per-chunk sums -> bsum[branch*16 + chunk]
__global__ __launch_bounds__(1024)
void scan_sum(const int* __restrict__ cnt, int* __restrict__ bsum, int n, int NC) {
  __shared__ int lsum[16];
  int br = blockIdx.x / NC, chunk = blockIdx.x - br * NC;
  int lane = threadIdx.x & 63, wv = threadIdx.x >> 6;
  const int* c = cnt + (size_t)br * n;
  int idx0 = chunk * 4096 + (int)threadIdx.x * 4;
  int s = 0;
  #pragma unroll
  for (int i = 0; i < 4; ++i) {
    int id = idx0 + i;
    s += (id < n) ? c[id] : 0;
  }
  #pragma unroll
  for (int off = 1; off < 64; off <<= 1) s += __shfl_xor(s, off);
  if (lane == 0) lsum[wv] = s;
  __syncthreads();
  if (threadIdx.x == 0) {
    int t = 0;
    for (int i = 0; i < 16; ++i) t += lsum[i];
    bsum[br * 16 + chunk] = t;
  }
}

// exclusive scan within chunk + bsum prefix base -> rp
__global__ __launch_bounds__(1024)
void scan_apply(const int* __restrict__ cnt, const int* __restrict__ bsum,
                int* __restrict__ rp, int n, int NC) {
  __shared__ int wsum[16];
  __shared__ int sBase;
  int br = blockIdx.x / NC, chunk = blockIdx.x - br * NC;
  int lane = threadIdx.x & 63, wv = threadIdx.x >> 6;
  const int* c = cnt + (size_t)br * n;
  int* r = rp + (size_t)br * (n + 1);
  if (threadIdx.x == 0) {
    int b = 0;
    for (int i = 0; i < chunk; ++i) b += bsum[br * 16 + i];
    sBase = b;
  }
  int idx0 = chunk * 4096 + (int)threadIdx.x * 4;
  int v[4], s = 0;
  #pragma unroll
  for (int i = 0; i < 4; ++i) {
    int id = idx0 + i;
    v[i] = (id < n) ? c[id] : 0;
    s += v[i];
  }
  int tot = s;
  #pragma unroll
  for (int off = 1; off < 64; off <<= 1) {
    int t = __shfl_up(s, off);
    if (lane >= off) s += t;
  }
  if (lane == 63) wsum[wv] = s;
  __syncthreads();
  if (wv == 0) {
    int xch = (lane < 16) ? wsum[lane] : 0;
    #pragma unroll
    for (int off = 1; off < 16; off <<= 1) {
      int t = __shfl_up(xch, off);
      if (lane >= off) xch += t;
    }
    if (lane < 16) wsum[lane] = xch;
  }
  __syncthreads();
  int run = sBase + (wv > 0 ? wsum[wv - 1] : 0) + (s - tot);
  #pragma unroll
  for (int i = 0; i < 4; ++i) {
    int id = idx0 + i;
    if (id < n) r[id] = run;
    run += v[i];
  }
  if (chunk == NC - 1 && threadIdx.x == 0) r[n] = sBase + wsum[15];
}

// scatter srcs into CSR order; atomicSub returns cnt to all-zero.
__global__ __launch_bounds__(256)
void scatter2_kernel(const int* __restrict__ s0, const int* __restrict__ s1,
                     const int* __restrict__ d0, const int* __restrict__ d1,
                     const int* __restrict__ rp, int* __restrict__ cnt,
                     int* __restrict__ sorted, int n, int E, int nb) {
  int br = blockIdx.x / nb;
  int i = (blockIdx.x - br * nb) * 256 + threadIdx.x;
  if (i >= E) return;
  const int* s = br ? s1 : s0;
  const int* d = br ? d1 : d0;
  int dd = d[i];
  int p = atomicSub(&cnt[br * n + dd], 1);
  sorted[(size_t)br * E + rp[(size_t)br * (n + 1) + dd] + p - 1] = s[i];
}

// ---------------- layer-0 fused embedding aggregation ----------------
__global__ __launch_bounds__(256)
void agg02_kernel(const int* __restrict__ x,
                  const float* __restrict__ s_t0, const float* __restrict__ s_t1,
                  const float* __restrict__ s_t2, const float* __restrict__ s_t3,
                  const float* __restrict__ s_t4,
                  const float* __restrict__ c_t0, const float* __restrict__ c_t1,
                  const float* __restrict__ c_t2, const float* __restrict__ c_t3,
                  const float* __restrict__ c_t4,
                  const int* __restrict__ rp0, const int* __restrict__ sorted0,
                  ushort* __restrict__ u) {
  __shared__ int lx[4][64 * 5];
  int br  = blockIdx.x / AGG0_NB;
  int blk = blockIdx.x - br * AGG0_NB;
  int w    = threadIdx.x >> 6;
  int wid  = blk * 4 + w;
  int lane = threadIdx.x & 63;
  if (wid >= cN1) return;
  const float* t0 = br ? c_t0 : s_t0;
  const float* t1 = br ? c_t1 : s_t1;
  const float* t2 = br ? c_t2 : s_t2;
  const float* t3 = br ? c_t3 : s_t3;
  const float* t4 = br ? c_t4 : s_t4;
  const float* gbase; int gxs, gstride;
  if (lane < 8)       { gbase = t0 + lane * 4;        gxs = 0; gstride = 32; }
  else if (lane < 12) { gbase = t1 + (lane - 8) * 4;  gxs = 1; gstride = 16; }
  else if (lane < 16) { gbase = t2 + (lane - 12) * 4; gxs = 2; gstride = 16; }
  else if (lane < 20) { gbase = t3 + (lane - 16) * 4; gxs = 3; gstride = 16; }
  else if (lane < 36) { gbase = t4 + (lane - 20) * 4; gxs = 4; gstride = 64; }
  else                { gbase = t0;                   gxs = 0; gstride = 0;  }
  int* lxw = lx[w];
  const int* rp   = rp0 + (size_t)br * (cN1 + 1);
  const int* srcs = sorted0 + (size_t)br * cE0;

  int beg = rp[wid], end = rp[wid + 1];
  float4 acc = make_float4(0.f, 0.f, 0.f, 0.f);
  for (int base = beg; base < end; base += 64) {
    int nn = min(64, end - base);
    if (lane < nn) {
      const int* xp = x + (size_t)srcs[base + lane] * 5;
      int v0 = xp[0], v1 = xp[1], v2 = xp[2], v3 = xp[3], v4 = xp[4];
      int* q = lxw + lane * 5;
      q[0] = v0; q[1] = v1; q[2] = v2; q[3] = v3; q[4] = v4;
    }
    int e = 0;
    for (; e + 8 <= nn; e += 8) {
      int rr[8];
      #pragma unroll
      for (int q = 0; q < 8; ++q) rr[q] = lxw[(e + q) * 5 + gxs];
      float4 g[8];
      #pragma unroll
      for (int q = 0; q < 8; ++q)
        g[q] = *reinterpret_cast<const float4*>(gbase + (size_t)rr[q] * gstride);
      #pragma unroll
      for (int q = 0; q < 8; ++q) {
        acc.x += g[q].x; acc.y += g[q].y; acc.z += g[q].z; acc.w += g[q].w;
      }
    }
    for (; e < nn; ++e) {
      int r = lxw[e * 5 + gxs];
      const float4 g = *reinterpret_cast<const float4*>(gbase + (size_t)r * gstride);
      acc.x += g.x; acc.y += g.y; acc.z += g.z; acc.w += g.w;
    }
  }
  float invc = (end > beg) ? 1.f / (float)(end - beg) : 0.f;
  ushort* ur = u + (size_t)br * UPLANE + (size_t)wid * KP;
  if (lane < 36) {
    const int* xd = x + (size_t)wid * 5;
    const float4 sv = *reinterpret_cast<const float4*>(gbase + (size_t)xd[gxs] * gstride);
    float4 r;
    r.x = sv.x + acc.x * invc;
    r.y = sv.y + acc.y * invc;
    r.z = sv.z + acc.z * invc;
    r.w = sv.w + acc.w * invc;
    ushort4 o;
    o.x = f2bf(r.x); o.y = f2bf(r.y); o.z = f2bf(r.z); o.w = f2bf(r.w);
    *reinterpret_cast<ushort4*>(ur + lane * 4) = o;
  } else if (lane < 40) {
    *reinterpret_cast<ushort4*>(ur + lane * 4) = make_ushort4(0, 0, 0, 0);
  }
}

// ---------------- W_in transpose+bf16+pad: Wt[2][256][KP] ----------------
__global__ __launch_bounds__(KP)
void build_wt2(const float* __restrict__ Ws, const float* __restrict__ Wc,
               ushort* __restrict__ Wt) {
  int br = blockIdx.x >> 8, n = blockIdx.x & 255, k = threadIdx.x;
  const float* W = br ? Wc : Ws;
  Wt[(size_t)br * HID * KP + n * KP + k] = (k < GD) ? f2bf(W[(size_t)k * HID + n]) : (ushort)0;
}

// ---------------- layer-0 MFMA GEMM: h1 = relu(u@Wt^T + bias*bm), bf16 out --
__global__ __launch_bounds__(256)
void gemm_mfma2(const ushort* __restrict__ U, const ushort* __restrict__ Wt,
                const float* __restrict__ bias_s, const float* __restrict__ bias_c,
                const int* __restrict__ rp0, ushort* __restrict__ h1) {
  int br  = blockIdx.x / NB1;
  int blk = blockIdx.x - br * NB1;
  int w = threadIdx.x >> 6, lane = threadIdx.x & 63;
  int l15 = lane & 15, lhi = lane >> 4;
  int rowW = blk * 64 + w * 16;
  const ushort* Up = U + (size_t)br * UPLANE;
  const ushort* Wp = Wt + (size_t)br * HID * KP;
  const float* bias = br ? bias_c : bias_s;
  const int* rp = rp0 + (size_t)br * (cN1 + 1);
  ushort* h1p = h1 + (size_t)br * cN1 * HID;

  f32x4 acc[16];
  #pragma unroll
  for (int t = 0; t < 16; ++t) acc[t] = (f32x4){0.f, 0.f, 0.f, 0.f};
  int arow = rowW + l15; if (arow >= cN1) arow = cN1 - 1;
  const ushort* up = Up + (size_t)arow * KP + lhi * 8;
  const ushort* wp = Wp + (size_t)l15 * KP + lhi * 8;
  #pragma unroll
  for (int ks = 0; ks < 5; ++ks) {
    bf16x8 a = *reinterpret_cast<const bf16x8*>(up + ks * 32);
    #pragma unroll
    for (int t = 0; t < 16; ++t) {
      bf16x8 b = *reinterpret_cast<const bf16x8*>(wp + (size_t)t * 16 * KP + ks * 32);
      acc[t] = __builtin_amdgcn_mfma_f32_16x16x32_bf16(a, b, acc[t], 0, 0, 0);
    }
  }
  int r0 = rowW + lhi * 4;
  #pragma unroll
  for (int r = 0; r < 4; ++r) {
    int row = r0 + r;
    if (row >= cN1) continue;
    float bm = (rp[row + 1] > rp[row]) ? 2.f : 1.f;
    #pragma unroll
    for (int t = 0; t < 16; ++t) {
      float val = acc[t][r] + bias[t * 16 + l15] * bm;
      h1p[(size_t)row * HID + t * 16 + l15] = f2bf(fmaxf(val, 0.f));
    }
  }
}

// ---------------- layer-1 aggregation -> V bf16 [N2][512] ----------------
__global__ __launch_bounds__(256)
void agg12_kernel(const ushort* __restrict__ h1, const int* __restrict__ rp1,
                  const int* __restrict__ sorted1, ushort* __restrict__ V) {
  int br  = blockIdx.x / AGG1_NB;
  int blk = blockIdx.x - br * AGG1_NB;
  int wid  = blk * 4 + (threadIdx.x >> 6);
  int lane = threadIdx.x & 63;
  if (wid >= cN2) return;
  const ushort* h1p = h1 + (size_t)br * cN1 * HID;
  const int* rp   = rp1 + (size_t)br * (cN2 + 1);
  const int* srcs = sorted1 + (size_t)br * cE1;
  int beg = rp[wid], end = rp[wid + 1];
  float4 acc = make_float4(0.f, 0.f, 0.f, 0.f);
  for (int base = beg; base < end; base += 64) {
    int nn = min(64, end - base);
    int se = (lane < nn) ? srcs[base + lane] : 0;
    int e = 0;
    for (; e + 4 <= nn; e += 4) {
      ushort4 hv[4];
      #pragma unroll
      for (int q = 0; q < 4; ++q) {
        int s = __shfl(se, e + q);
        hv[q] = *reinterpret_cast<const ushort4*>(h1p + (size_t)s * HID + lane * 4);
      }
      #pragma unroll
      for (int q = 0; q < 4; ++q) {
        acc.x += bf2f(hv[q].x); acc.y += bf2f(hv[q].y);
        acc.z += bf2f(hv[q].z); acc.w += bf2f(hv[q].w);
      }
    }
    for (; e < nn; ++e) {
      int s = __shfl(se, e);
      ushort4 hv = *reinterpret_cast<const ushort4*>(h1p + (size_t)s * HID + lane * 4);
      acc.x += bf2f(hv.x); acc.y += bf2f(hv.y); acc.z += bf2f(hv.z); acc.w += bf2f(hv.w);
    }
  }
  float invc = (end > beg) ? 1.f / (float)(end - beg) : 0.f;
  ushort4 dv = *reinterpret_cast<const ushort4*>(h1p + (size_t)wid * HID + lane * 4);
  ushort4 o;
  o.x = f2bf(bf2f(dv.x) + acc.x * invc);
  o.y = f2bf(bf2f(dv.y) + acc.y * invc);
  o.z = f2bf(bf2f(dv.z) + acc.z * invc);
  o.w = f2bf(bf2f(dv.w) + acc.w * invc);
  *reinterpret_cast<ushort4*>(V + (size_t)wid * KT + br * HID + lane * 4) = o;
}

// ---------------- integration weight folding ----------------
// M1 = c0*I + c2*Ws2c@Wc2s ; M2 = c1*Wc2s ; M3 = c1*Ws2c ; M4 = c0*I + c2*Wc2s@Ws2c
__global__ __launch_bounds__(128)
void build_small(const float* __restrict__ Ws2c, const float* __restrict__ Wc2s,
                 const float* __restrict__ a1p, const float* __restrict__ a2p,
                 const float* __restrict__ b2p, float* __restrict__ M) {
  int r = blockIdx.x, c = threadIdx.x;
  float A1 = a1p[0], A2 = a2p[0], B2 = b2p[0];
  float c0 = 1.f - A2 - B2;
  float c1 = A2 + B2 * (1.f - A1);
  float c2 = A1 * B2;
  float s1 = 0.f, s4 = 0.f;
  for (int k = 0; k < 128; ++k) {
    s1 += Ws2c[r * 128 + k] * Wc2s[k * 128 + c];
    s4 += Wc2s[r * 128 + k] * Ws2c[k * 128 + c];
  }
  float eye = (r == c) ? c0 : 0.f;
  M[0 * 16384 + r * 128 + c] = c2 * s1 + eye;
  M[1 * 16384 + r * 128 + c] = c1 * Wc2s[r * 128 + c];
  M[2 * 16384 + r * 128 + c] = c1 * Ws2c[r * 128 + c];
  M[3 * 16384 + r * 128 + c] = c2 * s4 + eye;
}

// Gt[j][k] bf16, j=out col (0..255: 0-127 z2sim, 128-255 z2cor), k=0..511
// rows k<256 use Wout_s, k>=256 use Wout_c.
__global__ __launch_bounds__(256)
void build_G(const float* __restrict__ Wout_s, const float* __restrict__ Wout_c,
             const float* __restrict__ M, ushort* __restrict__ Gt) {
  __shared__ float wr[128];
  int k = blockIdx.x, j = threadIdx.x;
  const float* wrow = (k < 256) ? &Wout_s[(size_t)k * 128] : &Wout_c[(size_t)(k - 256) * 128];
  if (j < 128) wr[j] = wrow[j];
  __syncthreads();
  const float* Mm = (j < 128) ? (k < 256 ? M : M + 16384)
                              : (k < 256 ? M + 2 * 16384 : M + 3 * 16384);
  int jj = j & 127;
  float s = 0.f;
  for (int t = 0; t < 128; ++t) s += wr[t] * Mm[t * 128 + jj];
  Gt[(size_t)j * KT + k] = f2bf(s);
}

__global__ __launch_bounds__(256)
void build_gvec(const float* __restrict__ b_s, const float* __restrict__ b_c,
                const float* __restrict__ M, float* __restrict__ gvec) {
  int j = threadIdx.x, jj = j & 127;
  const float* Ma = (j < 128) ? M : M + 2 * 16384;
  const float* Mb = (j < 128) ? M + 16384 : M + 3 * 16384;
  float s = 0.f;
  for (int t = 0; t < 128; ++t)
    s += b_s[t] * Ma[t * 128 + jj] + b_c[t] * Mb[t * 128 + jj];
  gvec[j] = s;
}

// ---------------- tail MFMA GEMM: out = V @ Gt^T + gvec ----------------
__global__ __launch_bounds__(64)
void tail_gemm(const ushort* __restrict__ V, const ushort* __restrict__ Gt,
               const float* __restrict__ gvec, float* __restrict__ out) {
  int lane = threadIdx.x;
  int l15 = lane & 15, lhi = lane >> 4;
  int rowW = blockIdx.x * 16;
  f32x4 acc[16];
  #pragma unroll
  for (int t = 0; t < 16; ++t) acc[t] = (f32x4){0.f, 0.f, 0.f, 0.f};
  const ushort* vp = V + (size_t)(rowW + l15) * KT + lhi * 8;
  const ushort* gp = Gt + (size_t)l15 * KT + lhi * 8;
  #pragma unroll
  for (int ks = 0; ks < 16; ++ks) {
    bf16x8 a = *reinterpret_cast<const bf16x8*>(vp + ks * 32);
    #pragma unroll
    for (int t = 0; t < 16; ++t) {
      bf16x8 b = *reinterpret_cast<const bf16x8*>(gp + (size_t)t * 16 * KT + ks * 32);
      acc[t] = __builtin_amdgcn_mfma_f32_16x16x32_bf16(a, b, acc[t], 0, 0, 0);
    }
  }
  int r0 = rowW + lhi * 4;
  #pragma unroll
  for (int t = 0; t < 16; ++t) {
    int col = t * 16 + l15;
    float gv = gvec[col];
    float* dst = (col < 128) ? out + (size_t)r0 * OUTD + col
                             : out + (size_t)cN2 * OUTD + (size_t)r0 * OUTD + (col - 128);
    #pragma unroll
    for (int r = 0; r < 4; ++r)
      dst[(size_t)r * OUTD] = acc[t][r] + gv;
  }
}

// ---------------- launch ----------------
extern "C" void kernel_launch(void* const* d_in, const int* in_sizes, int n_in,
                              void* d_out, int out_size, void* d_ws, size_t ws_size,
                              hipStream_t stream) {
  const int* x = (const int*)d_in[0];
  struct Branch {
    const int *e0s, *e0d, *e1s, *e1d;
    const float *t0, *t1, *t2, *t3, *t4, *Win, *bin, *Wout, *bout;
  };
  auto mk = [&](int b) {
    Branch B;
    B.e0s = (const int*)d_in[b + 0];
    B.e0d = (const int*)d_in[b + 1];
    B.e1s = (const int*)d_in[b + 2];
    B.e1d = (const int*)d_in[b + 3];
    B.t0  = (const float*)d_in[b + 4];
    B.t1  = (const float*)d_in[b + 5];
    B.t2  = (const float*)d_in[b + 6];
    B.t3  = (const float*)d_in[b + 7];
    B.t4  = (const float*)d_in[b + 8];
    B.Win = (const float*)d_in[b + 9];
    B.bin = (const float*)d_in[b + 10];
    B.Wout= (const float*)d_in[b + 11];
    B.bout= (const float*)d_in[b + 12];
    return B;
  };
  Branch SB = mk(1), CB = mk(14);
  const float* Ws2c = (const float*)d_in[27];
  const float* Wc2s = (const float*)d_in[28];
  const float* a1p  = (const float*)d_in[29];
  const float* a2p  = (const float*)d_in[30];
  const float* b2p  = (const float*)d_in[31];

  // workspace layout
  char* ws = (char*)d_ws;
  ushort* u    = (ushort*)(ws + 0);            // 2*50048*160*2 = 32,030,720
  ushort* h1   = (ushort*)(ws + 32030720);     // 2*50000*256*2 = 51,200,000
  ushort* V    = (ushort*)(ws + 83230720);     // 10000*512*2   = 10,240,000
  float*  M    = (float*) (ws + 93470720);     // 4*128*128*4   = 262,144
  ushort* Gt   = (ushort*)(ws + 93732864);     // 256*512*2     = 262,144
  float*  gvec = (float*) (ws + 93995008);     // 1,024
  ushort* Wt   = (ushort*)(ws + 93996032);     // 2*256*160*2   = 163,840
  int* rp0     = (int*)   (ws + 94159872);     // 2*50001*4     = 400,008
  int* cnt     = (int*)   (ws + 94560128);     // 2*50000*4     = 400,000
  int* cnt1    = (int*)   (ws + 94960128);     // 2*10000*4     = 80,000 (contiguous w/ cnt)
  int* rp1     = (int*)   (ws + 95040384);     // 2*10001*4     = 80,008
  int* bsum    = (int*)   (ws + 95120640);     // 32*4
  int* sorted0 = (int*)   (ws + 95121024);     // 2*800000*4    = 6,400,000
  int* sorted1 = (int*)   (ws + 101521024);    // 2*160000*4    = 1,280,000 (end ~102.8MB)

  // one memset covers cnt + cnt1 (contiguous 480,256 bytes incl. gap)
  hipMemsetAsync(cnt, 0, 480256, stream);

  // weight folding (independent)
  build_wt2<<<512, KP, 0, stream>>>(SB.Win, CB.Win, Wt);
  build_small<<<128, 128, 0, stream>>>(Ws2c, Wc2s, a1p, a2p, b2p, M);
  build_G<<<512, 256, 0, stream>>>(SB.Wout, CB.Wout, M, Gt);
  build_gvec<<<1, 256, 0, stream>>>(SB.bout, CB.bout, M, gvec);

  // layer-0 CSR (both branches)
  count2_kernel<<<2 * NB_E0, 256, 0, stream>>>(SB.e0d, CB.e0d, cnt, cN1, cE0, NB_E0);
  scan_sum<<<2 * NC0, 1024, 0, stream>>>(cnt, bsum, cN1, NC0);
  scan_apply<<<2 * NC0, 1024, 0, stream>>>(cnt, bsum, rp0, cN1, NC0);
  scatter2_kernel<<<2 * NB_E0, 256, 0, stream>>>(SB.e0s, CB.e0s, SB.e0d, CB.e0d,
                                                 rp0, cnt, sorted0, cN1, cE0, NB_E0);
  // layer-1 CSR (both branches)
  count2_kernel<<<2 * NB_E1, 256, 0, stream>>>(SB.e1d, CB.e1d, cnt1, cN2, cE1, NB_E1);
  scan_sum<<<2 * NC1, 1024, 0, stream>>>(cnt1, bsum, cN2, NC1);
  scan_apply<<<2 * NC1, 1024, 0, stream>>>(cnt1, bsum, rp1, cN2, NC1);
  scatter2_kernel<<<2 * NB_E1, 256, 0, stream>>>(SB.e1s, CB.e1s, SB.e1d, CB.e1d,
                                                 rp1, cnt1, sorted1, cN2, cE1, NB_E1);

  // compute pipeline
  agg02_kernel<<<2 * AGG0_NB, 256, 0, stream>>>(x,
      SB.t0, SB.t1, SB.t2, SB.t3, SB.t4,
      CB.t0, CB.t1, CB.t2, CB.t3, CB.t4,
      rp0, sorted0, u);
  gemm_mfma2<<<2 * NB1, 256, 0, stream>>>(u, Wt, SB.bin, CB.bin, rp0, h1);
  agg12_kernel<<<2 * AGG1_NB, 256, 0, stream>>>(h1, rp1, sorted1, V);
  tail_gemm<<<TAIL_NB, 64, 0, stream>>>(V, Gt, gvec, (float*)d_out);
}